// Round 3
// baseline (171.756 us; speedup 1.0000x reference)
//
#include <hip/hip_runtime.h>

// EdgeNetwork, counting-sort + MFMA + run-merged scatter.
//
// R2 post-mortem: occupancy doubling left time/WRITE_SIZE unchanged ->
// edge_fused is throughput-bound on 12.8M single-dword device-scope atomic
// RMWs (225G/s at the coherence point), not latency-bound.
// R3: sort edges by destination (counting sort: hist -> 2-level scan ->
// scatter), permute edge->MFMA-row so each lane owns 8 CONSECUTIVE sorted
// edges, merge equal-dst runs in registers -> ~3x fewer atomic dwords.
// NOTE (R0): no hipLaunchCooperativeKernel here (graph capture no-ops it).

typedef _Float16 half8 __attribute__((ext_vector_type(8)));
typedef _Float16 half4t __attribute__((ext_vector_type(4)));
typedef float float4v __attribute__((ext_vector_type(4)));

constexpr int NA = 100000;
constexpr int E  = 400000;
constexpr int TILES = E / 32;          // 12500
constexpr int NBLK  = 768;             // 3 blocks/CU (R0 best-known config)
constexpr int HALFW = NBLK * 4 / 2;    // 1536 waves per column-half
constexpr int NCHUNK = (NA + 1023) / 1024;   // 98 scan chunks

// ---- workspace layout (bytes) ----
constexpr size_t OFF_ATOMH = 0;                          // f16[NA*32]   6.40 MB
constexpr size_t OFF_BONDS = (size_t)NA * 32 * 2;        // f16[E*16]   12.80 MB (sorted)
constexpr size_t OFF_PAIRS = OFF_BONDS + (size_t)E*16*2; // int2[E]      3.20 MB (sorted)
constexpr size_t OFF_HIST  = OFF_PAIRS + (size_t)E*8;    // u32[NA]      0.40 MB
constexpr size_t OFF_BASE  = OFF_HIST + (size_t)NA*4;    // u32[NA]      0.40 MB
constexpr size_t OFF_BSUM  = OFF_BASE + (size_t)NA*4;    // u32[128]
constexpr size_t OFF_BOFF  = OFF_BSUM + 512;             // u32[128]

constexpr int NZ4 = NA * 32 / 4;   // out zeroing, float4 units   (800k)
constexpr int NA4 = NA * 32 / 4;   // atom convert, float4 units  (800k)
constexpr int NH4 = NA / 4;        // hist zeroing, uint4 units   (25k)
constexpr int K0_TOT = NZ4 + NA4 + NH4;

// ---- k0: zero out + zero hist + convert atom f32->f16 ----
__global__ void k_zero_conv(const float* __restrict__ atom,
                            float4* __restrict__ outz,
                            half4t* __restrict__ atomh4,
                            uint4* __restrict__ histz) {
  int i = blockIdx.x * 256 + threadIdx.x;
  if (i < NZ4) {
    outz[i] = make_float4(0.f, 0.f, 0.f, 0.f);
  } else if (i < NZ4 + NA4) {
    int k = i - NZ4;
    float4 v = ((const float4*)atom)[k];
    half4t hh = { (_Float16)v.x, (_Float16)v.y, (_Float16)v.z, (_Float16)v.w };
    atomh4[k] = hh;
  } else if (i < K0_TOT) {
    int k = i - NZ4 - NA4;
    histz[k] = make_uint4(0u, 0u, 0u, 0u);
  }
}

// ---- k1: histogram of destinations ----
__global__ void k_hist(const int2* __restrict__ pairs2,
                       unsigned* __restrict__ hist) {
  int e = blockIdx.x * 256 + threadIdx.x;
  if (e >= E) return;
  atomicAdd(&hist[(unsigned)pairs2[e].x], 1u);
}

// ---- k2: per-1024-chunk exclusive scan of hist -> base, chunk totals -> bsum
__global__ void k_scan_chunks(const unsigned* __restrict__ hist,
                              unsigned* __restrict__ base,
                              unsigned* __restrict__ bsum) {
  __shared__ unsigned s[256];
  const int t  = threadIdx.x;
  const int i0 = blockIdx.x * 1024 + t * 4;
  unsigned c[4], sum = 0;
  #pragma unroll
  for (int j = 0; j < 4; ++j) {
    unsigned v = (i0 + j < NA) ? hist[i0 + j] : 0u;
    c[j] = v; sum += v;
  }
  s[t] = sum;
  __syncthreads();
  for (int off = 1; off < 256; off <<= 1) {   // Hillis-Steele inclusive
    unsigned v = (t >= off) ? s[t - off] : 0u;
    __syncthreads();
    s[t] += v;
    __syncthreads();
  }
  if (t == 255) bsum[blockIdx.x] = s[255];
  unsigned run = (t == 0) ? 0u : s[t - 1];
  #pragma unroll
  for (int j = 0; j < 4; ++j) {
    if (i0 + j < NA) base[i0 + j] = run;
    run += c[j];
  }
}

// ---- k3: exclusive scan of the 98 chunk totals ----
__global__ void k_scan_tops(const unsigned* __restrict__ bsum,
                            unsigned* __restrict__ boff) {
  __shared__ unsigned s[128];
  const int t = threadIdx.x;   // 128 threads
  s[t] = (t < NCHUNK) ? bsum[t] : 0u;
  __syncthreads();
  for (int off = 1; off < 128; off <<= 1) {
    unsigned v = (t >= off) ? s[t - off] : 0u;
    __syncthreads();
    s[t] += v;
    __syncthreads();
  }
  if (t < NCHUNK) boff[t] = (t == 0) ? 0u : s[t - 1];
}

// ---- k4: scatter edges into dst-sorted order; convert bond rows to f16 ----
__global__ void k_scatter(const int2* __restrict__ pairs2,
                          const float4* __restrict__ bondf4,
                          unsigned* __restrict__ hist,
                          const unsigned* __restrict__ base,
                          const unsigned* __restrict__ boff,
                          int2* __restrict__ pairs_s,
                          half8* __restrict__ bondh_s) {
  int e = blockIdx.x * 256 + threadIdx.x;
  if (e >= E) return;
  int2 p = pairs2[e];
  unsigned d = (unsigned)p.x;
  unsigned pos = base[d] + boff[d >> 10] + (atomicSub(&hist[d], 1u) - 1u);
  pairs_s[pos] = p;
  float4 b0 = bondf4[e * 4 + 0], b1 = bondf4[e * 4 + 1];
  float4 b2 = bondf4[e * 4 + 2], b3 = bondf4[e * 4 + 3];
  half8 h0 = { (_Float16)b0.x, (_Float16)b0.y, (_Float16)b0.z, (_Float16)b0.w,
               (_Float16)b1.x, (_Float16)b1.y, (_Float16)b1.z, (_Float16)b1.w };
  half8 h1 = { (_Float16)b2.x, (_Float16)b2.y, (_Float16)b2.z, (_Float16)b2.w,
               (_Float16)b3.x, (_Float16)b3.y, (_Float16)b3.z, (_Float16)b3.w };
  bondh_s[(size_t)pos * 2 + 0] = h0;
  bondh_s[(size_t)pos * 2 + 1] = h1;
}

static __device__ inline half8 splat8(_Float16 v) {
  half8 r = {v, v, v, v, v, v, v, v};
  return r;
}

// ---- k5: MFMA GEMM + run-merged scatter over sorted edges ----
// Edge->row permutation: tile row (acc0, rowA=q*4+r) <-> local edge q*8+r;
// (acc1, rowB) <-> local edge q*8+4+r. Lane (q,el)'s 8 acc values are edges
// q*8+0..7 IN SORTED ORDER -> merge equal-dst runs before atomics.
__global__ __launch_bounds__(256, 3)
void edge_sorted(const _Float16* __restrict__ atomh,
                 const _Float16* __restrict__ bondh,
                 const int* __restrict__ pairs_s,
                 const float* __restrict__ Kmat,
                 const float* __restrict__ bias,
                 float* __restrict__ out)
{
  const int tid  = threadIdx.x;
  const int lane = tid & 63;
  const int wid  = blockIdx.x * 4 + (tid >> 6);
  const int h    = wid & 1;          // column half this wave owns
  const int q    = lane >> 4;
  const int el   = lane & 15;
  const int n    = el + h * 16;      // output column
  const int j0   = q * 8;
  const int eA   = ((el >> 2) * 8) + (el & 3);   // local edge for A-row el

  // W fragments for all 17 K-steps, register-resident.
  half8 Wr[17];
  #pragma unroll
  for (int s = 0; s < 17; ++s) {
    const float* src = (s < 16) ? (Kmat + s * 1024 + n * 32 + j0)
                                : (bias + n * 32 + j0);
    half8 w;
    #pragma unroll
    for (int j = 0; j < 8; ++j) w[j] = (_Float16)src[j];
    Wr[s] = w;
  }

  const int start  = wid >> 1;
  const int stride = HALFW;
  const int2* pairs2 = (const int2*)pairs_s;

  auto ldpv = [&](int t) -> int2 {
    const int tc = t < TILES ? t : TILES - 1;   // clamp: loads stay valid
    int2 v = make_int2(0, 0);
    if (lane < 32) v = pairs2[tc * 32 + lane];
    return v;
  };

  // ---- Pipeline prologue.
  int2 pv0 = ldpv(start);
  int2 pv1 = ldpv(start + stride);

  half8 nbA_c, nbB_c, bA0_c, bA1_c, bB0_c, bB1_c;
  {
    const int aA = __shfl(pv0.y, eA);
    const int aB = __shfl(pv0.y, eA + 4);
    nbA_c = *(const half8*)(atomh + (size_t)aA * 32 + j0);
    nbB_c = *(const half8*)(atomh + (size_t)aB * 32 + j0);
    const _Float16* brA = bondh + (size_t)(start * 32 + eA) * 16;
    const _Float16* brB = bondh + (size_t)(start * 32 + eA + 4) * 16;
    bA0_c = *(const half8*)(brA);  bA1_c = *(const half8*)(brA + 8);
    bB0_c = *(const half8*)(brB);  bB1_c = *(const half8*)(brB + 8);
  }

  for (int t = start; t < TILES; t += stride) {
    const int tn = t + stride;

    // ---- Stage next tile (loads in flight across this tile's compute).
    half8 nbA_n, nbB_n, bA0_n, bA1_n, bB0_n, bB1_n;
    {
      const int aA = __shfl(pv1.y, eA);
      const int aB = __shfl(pv1.y, eA + 4);
      nbA_n = *(const half8*)(atomh + (size_t)aA * 32 + j0);
      nbB_n = *(const half8*)(atomh + (size_t)aB * 32 + j0);
      const int tc = tn < TILES ? tn : TILES - 1;
      const _Float16* brA = bondh + (size_t)(tc * 32 + eA) * 16;
      const _Float16* brB = bondh + (size_t)(tc * 32 + eA + 4) * 16;
      bA0_n = *(const half8*)(brA);  bA1_n = *(const half8*)(brA + 8);
      bB0_n = *(const half8*)(brB);  bB1_n = *(const half8*)(brB + 8);
    }
    const int2 pv2 = ldpv(tn + stride);

    // ---- Compute current tile.
    float4v acc0 = {0.f, 0.f, 0.f, 0.f};
    float4v acc1 = {0.f, 0.f, 0.f, 0.f};
    #pragma unroll
    for (int s = 0; s < 16; ++s) {
      const _Float16 sA = (s < 8) ? bA0_c[s] : bA1_c[s - 8];
      const _Float16 sB = (s < 8) ? bB0_c[s] : bB1_c[s - 8];
      const half8 aAf = nbA_c * splat8(sA);
      const half8 aBf = nbB_c * splat8(sB);
      acc0 = __builtin_amdgcn_mfma_f32_16x16x32_f16(aAf, Wr[s], acc0, 0, 0, 0);
      acc1 = __builtin_amdgcn_mfma_f32_16x16x32_f16(aBf, Wr[s], acc1, 0, 0, 0);
    }
    acc0 = __builtin_amdgcn_mfma_f32_16x16x32_f16(nbA_c, Wr[16], acc0, 0, 0, 0);
    acc1 = __builtin_amdgcn_mfma_f32_16x16x32_f16(nbB_c, Wr[16], acc1, 0, 0, 0);

    // ---- Epilogue: merge equal-dst runs over the lane's 8 sorted edges.
    {
      int   cur = __shfl(pv0.x, q * 8);
      float run = acc0[0];
      #pragma unroll
      for (int m = 1; m < 8; ++m) {
        const float v  = (m < 4) ? acc0[m] : acc1[m - 4];
        const int   dm = __shfl(pv0.x, q * 8 + m);
        if (dm == cur) {
          run += v;
        } else {
          atomicAdd(out + (size_t)cur * 32 + n, run);
          run = v; cur = dm;
        }
      }
      atomicAdd(out + (size_t)cur * 32 + n, run);
    }

    // ---- Rotate pipeline registers.
    pv0 = pv1; pv1 = pv2;
    nbA_c = nbA_n; nbB_c = nbB_n;
    bA0_c = bA0_n; bA1_c = bA1_n; bB0_c = bB0_n; bB1_c = bB1_n;
  }
}

extern "C" void kernel_launch(void* const* d_in, const int* in_sizes, int n_in,
                              void* d_out, int out_size, void* d_ws, size_t ws_size,
                              hipStream_t stream) {
  const float* atom  = (const float*)d_in[0];   // (100000, 32) f32
  const float* bondf = (const float*)d_in[1];   // (400000, 16) f32
  const int*   pairs = (const int*)d_in[2];     // (400000, 2) int32
  const float* Kmat  = (const float*)d_in[3];   // (16, 1024) f32
  const float* bias  = (const float*)d_in[4];   // (1024,) f32
  float* out = (float*)d_out;                   // (100000, 32) f32

  char* ws = (char*)d_ws;
  _Float16* atomh   = (_Float16*)(ws + OFF_ATOMH);
  _Float16* bondh_s = (_Float16*)(ws + OFF_BONDS);
  int2*     pairs_s = (int2*)    (ws + OFF_PAIRS);
  unsigned* hist    = (unsigned*)(ws + OFF_HIST);
  unsigned* base    = (unsigned*)(ws + OFF_BASE);
  unsigned* bsum    = (unsigned*)(ws + OFF_BSUM);
  unsigned* boff    = (unsigned*)(ws + OFF_BOFF);

  k_zero_conv<<<(K0_TOT + 255) / 256, 256, 0, stream>>>(
      atom, (float4*)out, (half4t*)atomh, (uint4*)hist);
  k_hist<<<(E + 255) / 256, 256, 0, stream>>>((const int2*)pairs, hist);
  k_scan_chunks<<<NCHUNK, 256, 0, stream>>>(hist, base, bsum);
  k_scan_tops<<<1, 128, 0, stream>>>(bsum, boff);
  k_scatter<<<(E + 255) / 256, 256, 0, stream>>>(
      (const int2*)pairs, (const float4*)bondf, hist, base, boff,
      pairs_s, (half8*)bondh_s);
  edge_sorted<<<NBLK, 256, 0, stream>>>(
      atomh, bondh_s, (const int*)pairs_s, Kmat, bias, out);
}